// Round 1
// baseline (125.978 us; speedup 1.0000x reference)
//
#include <hip/hip_runtime.h>

// frames: [N=16, B=4, C=64, H=128, W=128] fp32
// out[i] = frames[i]^2 * sum_j frames[j]
// Single-pass: each thread owns one float4 of the inner M = B*C*H*W elements,
// loads all 16 frame values, reduces in registers, writes 16 outputs.

constexpr int N_FRAMES = 16;
constexpr int M_ELEMS  = 4 * 64 * 128 * 128;   // 4,194,304 fp32 per frame
constexpr int M4       = M_ELEMS / 4;          // 1,048,576 float4 per frame

__global__ __launch_bounds__(256) void frame_similarly_kernel(
    const float4* __restrict__ in, float4* __restrict__ out) {
    int e = blockIdx.x * blockDim.x + threadIdx.x;
    if (e >= M4) return;

    float4 v[N_FRAMES];
    float4 s = make_float4(0.f, 0.f, 0.f, 0.f);

    #pragma unroll
    for (int i = 0; i < N_FRAMES; ++i) {
        v[i] = in[(size_t)i * M4 + e];
    }
    #pragma unroll
    for (int i = 0; i < N_FRAMES; ++i) {
        s.x += v[i].x; s.y += v[i].y; s.z += v[i].z; s.w += v[i].w;
    }
    #pragma unroll
    for (int i = 0; i < N_FRAMES; ++i) {
        float4 o;
        o.x = v[i].x * v[i].x * s.x;
        o.y = v[i].y * v[i].y * s.y;
        o.z = v[i].z * v[i].z * s.z;
        o.w = v[i].w * v[i].w * s.w;
        out[(size_t)i * M4 + e] = o;
    }
}

extern "C" void kernel_launch(void* const* d_in, const int* in_sizes, int n_in,
                              void* d_out, int out_size, void* d_ws, size_t ws_size,
                              hipStream_t stream) {
    const float4* in  = (const float4*)d_in[0];
    float4*       out = (float4*)d_out;

    const int threads = 256;
    const int blocks  = (M4 + threads - 1) / threads;  // 4096
    frame_similarly_kernel<<<blocks, threads, 0, stream>>>(in, out);
}

// Round 3
// 120.982 us; speedup vs baseline: 1.0413x; 1.0413x over previous
//
#include <hip/hip_runtime.h>

// frames: [N=16, B=4, C=64, H=128, W=128] fp32
// out[i] = frames[i]^2 * sum_j frames[j]
// Single-pass: each thread owns one float4 of the inner M = B*C*H*W elements,
// loads all 16 frame values (nontemporal), reduces in registers, writes 16
// outputs (nontemporal). Data is touched exactly once -> bypass caches.
// Use native clang vector type so __builtin_nontemporal_* accepts it.

typedef float f32x4 __attribute__((ext_vector_type(4)));

constexpr int N_FRAMES = 16;
constexpr int M_ELEMS  = 4 * 64 * 128 * 128;   // 4,194,304 fp32 per frame
constexpr int M4       = M_ELEMS / 4;          // 1,048,576 float4 per frame

__global__ __launch_bounds__(256) void frame_similarly_kernel(
    const f32x4* __restrict__ in, f32x4* __restrict__ out) {
    int e = blockIdx.x * blockDim.x + threadIdx.x;
    if (e >= M4) return;

    f32x4 v[N_FRAMES];
    f32x4 s = (f32x4)(0.f, 0.f, 0.f, 0.f);

    #pragma unroll
    for (int i = 0; i < N_FRAMES; ++i) {
        v[i] = __builtin_nontemporal_load(&in[(size_t)i * M4 + e]);
    }
    #pragma unroll
    for (int i = 0; i < N_FRAMES; ++i) {
        s += v[i];
    }
    #pragma unroll
    for (int i = 0; i < N_FRAMES; ++i) {
        f32x4 o = v[i] * v[i] * s;
        __builtin_nontemporal_store(o, &out[(size_t)i * M4 + e]);
    }
}

extern "C" void kernel_launch(void* const* d_in, const int* in_sizes, int n_in,
                              void* d_out, int out_size, void* d_ws, size_t ws_size,
                              hipStream_t stream) {
    const f32x4* in  = (const f32x4*)d_in[0];
    f32x4*       out = (f32x4*)d_out;

    const int threads = 256;
    const int blocks  = (M4 + threads - 1) / threads;  // 4096
    frame_similarly_kernel<<<blocks, threads, 0, stream>>>(in, out);
}

// Round 4
// 109.122 us; speedup vs baseline: 1.1545x; 1.1087x over previous
//
#include <hip/hip_runtime.h>

// frames: [N=16, B=4, C=64, H=128, W=128] fp32
// out[i] = frames[i]^2 * sum_j frames[j]
// Single-pass, one f32x2 per thread: 16 nt-loads -> register sum -> 16 nt-stores.
// f32x2 (not f32x4) halves live VGPRs (64->32) so we fit 8 waves/SIMD instead
// of 4: doubles resident waves to smooth the bursty 16-load/16-store pattern.

typedef float f32x2 __attribute__((ext_vector_type(2)));

constexpr int N_FRAMES = 16;
constexpr int M_ELEMS  = 4 * 64 * 128 * 128;   // 4,194,304 fp32 per frame
constexpr int M2       = M_ELEMS / 2;          // 2,097,152 f32x2 per frame

__global__ __launch_bounds__(256, 8) void frame_similarly_kernel(
    const f32x2* __restrict__ in, f32x2* __restrict__ out) {
    int e = blockIdx.x * blockDim.x + threadIdx.x;   // grid exactly covers M2

    f32x2 v[N_FRAMES];
    f32x2 s = (f32x2)(0.f, 0.f);

    #pragma unroll
    for (int i = 0; i < N_FRAMES; ++i) {
        v[i] = __builtin_nontemporal_load(&in[(size_t)i * M2 + e]);
    }
    #pragma unroll
    for (int i = 0; i < N_FRAMES; ++i) {
        s += v[i];
    }
    #pragma unroll
    for (int i = 0; i < N_FRAMES; ++i) {
        f32x2 o = v[i] * v[i] * s;
        __builtin_nontemporal_store(o, &out[(size_t)i * M2 + e]);
    }
}

extern "C" void kernel_launch(void* const* d_in, const int* in_sizes, int n_in,
                              void* d_out, int out_size, void* d_ws, size_t ws_size,
                              hipStream_t stream) {
    const f32x2* in  = (const f32x2*)d_in[0];
    f32x2*       out = (f32x2*)d_out;

    const int threads = 256;
    const int blocks  = M2 / threads;  // 8192, exact
    frame_similarly_kernel<<<blocks, threads, 0, stream>>>(in, out);
}

// Round 5
// 93.359 us; speedup vs baseline: 1.3494x; 1.1688x over previous
//
#include <hip/hip_runtime.h>

// frames: [N=16, B=4, C=64, H=128, W=128] fp32
// out[i] = frames[i]^2 * sum_j frames[j]
// Single-pass, one f32x2 per thread: 16 nt-loads -> register sum -> 16 stores.
// nt on LOADS only (single-use data, keep out of L2); stores are regular
// write-back so they batch in L2 and drain to HBM in large bursts instead of
// forcing fine-grained read/write turnarounds on the DRAM bus.

typedef float f32x2 __attribute__((ext_vector_type(2)));

constexpr int N_FRAMES = 16;
constexpr int M_ELEMS  = 4 * 64 * 128 * 128;   // 4,194,304 fp32 per frame
constexpr int M2       = M_ELEMS / 2;          // 2,097,152 f32x2 per frame

__global__ __launch_bounds__(256, 8) void frame_similarly_kernel(
    const f32x2* __restrict__ in, f32x2* __restrict__ out) {
    int e = blockIdx.x * blockDim.x + threadIdx.x;   // grid exactly covers M2

    f32x2 v[N_FRAMES];
    f32x2 s = (f32x2)(0.f, 0.f);

    #pragma unroll
    for (int i = 0; i < N_FRAMES; ++i) {
        v[i] = __builtin_nontemporal_load(&in[(size_t)i * M2 + e]);
    }
    #pragma unroll
    for (int i = 0; i < N_FRAMES; ++i) {
        s += v[i];
    }
    #pragma unroll
    for (int i = 0; i < N_FRAMES; ++i) {
        f32x2 o = v[i] * v[i] * s;
        out[(size_t)i * M2 + e] = o;   // regular write-back store
    }
}

extern "C" void kernel_launch(void* const* d_in, const int* in_sizes, int n_in,
                              void* d_out, int out_size, void* d_ws, size_t ws_size,
                              hipStream_t stream) {
    const f32x2* in  = (const f32x2*)d_in[0];
    f32x2*       out = (f32x2*)d_out;

    const int threads = 256;
    const int blocks  = M2 / threads;  // 8192, exact
    frame_similarly_kernel<<<blocks, threads, 0, stream>>>(in, out);
}